// Round 6
// baseline (53193.048 us; speedup 1.0000x reference)
//
#include <hip/hip_runtime.h>
#include <cstdint>

// TinyVanillaRNN: T=16384 sequential steps h = tanh(U[:,x_t] + W h + bh);
// logits[t] = V h_t + by. out = [logits (T*O) | h_T (H)], fp32.
//
// R6: DPP reduction + fast-channel-only publish.
//  - Election (R5-proven): 256 blocks register XCC_ID; 32nd registrant on any
//    XCD elects it (pigeonhole -> always resolves). Ranks 0..31 = workers.
//  - Startup canary handshake (bounded) picks channel mode once, globally:
//    mode FAST = volatile stores/loads through the XCD-local L2 (R5-verified:
//    FETCH_SIZE 547->70 MB); mode SLOW = R3's agent-scope atomics. Hang-proof.
//  - Reduce: DPP ladder (row_shr 1/2/4/8 + row_bcast 15/31) — pure VALU,
//    replaces 7 serialized ds_swizzle shuffles (~120 cy each, the R3/R5
//    critical-path term betrayed by SQ_LDS_BANK_CONFLICT=6.7e7). Row sums
//    land in lane 63, which applies tanh and publishes 4 tagged u64s.
//  - Matvec uses v_pk_fma_f32 (float2 elementwise fma).

constexpr int T_STEPS = 16384;
constexpr int D_DIM   = 512;
constexpr int H_DIM   = 1024;
constexpr int O_DIM   = 512;
constexpr int NGRID   = 256;
constexpr int NWORK   = 32;
constexpr int NTHR    = 512;

typedef float v2f __attribute__((ext_vector_type(2)));

__device__ __forceinline__ float fast_tanh(float x) {
    float e = __expf(2.f * x);
    return 1.f - 2.f / (e + 1.f);
}

// x += lane-shifted x (DPP). old=0 + bound_ctrl=1 -> invalid lanes add 0.
template<int CTRL>
__device__ __forceinline__ float dpp_add(float x) {
    int m = __builtin_amdgcn_update_dpp(0, __float_as_int(x), CTRL, 0xf, 0xf, true);
    return x + __int_as_float(m);
}
// Full 64-lane sum; result valid in lane 63.
__device__ __forceinline__ float wave_sum_dpp(float x) {
    x = dpp_add<0x111>(x);   // row_shr:1
    x = dpp_add<0x112>(x);   // row_shr:2
    x = dpp_add<0x114>(x);   // row_shr:4
    x = dpp_add<0x118>(x);   // row_shr:8  -> lane15 of each 16-row = row sum
    x = dpp_add<0x142>(x);   // row_bcast:15 -> lane31/63 = 32-half sums
    x = dpp_add<0x143>(x);   // row_bcast:31 -> lane63 = full sum
    return x;
}

__global__ __launch_bounds__(NTHR, 2)
void rnn_fused(const int* __restrict__ xs, const float* __restrict__ h0,
               const float* __restrict__ U, const float* __restrict__ W,
               const float* __restrict__ V, const float* __restrict__ bh,
               const float* __restrict__ by, float* __restrict__ out,
               int* __restrict__ ctrl, unsigned long long* __restrict__ htag)
{
    const int tid = threadIdx.x;

    // ---- election: find 32 co-XCD blocks (pigeonhole over 256) ----
    __shared__ int s_slice, s_mode;
    if (tid == 0) {
        int xcd;
        asm volatile("s_getreg_b32 %0, hwreg(HW_REG_XCC_ID)" : "=s"(xcd));
        xcd &= 7;
        const int r = __hip_atomic_fetch_add(&ctrl[1 + xcd], 1,
                                             __ATOMIC_RELAXED, __HIP_MEMORY_SCOPE_AGENT);
        if (r == NWORK - 1) {
            int expected = 0;
            __hip_atomic_compare_exchange_strong(&ctrl[0], &expected, xcd + 1,
                __ATOMIC_RELAXED, __ATOMIC_RELAXED, __HIP_MEMORY_SCOPE_AGENT);
        }
        int ch;
        do {
            ch = __hip_atomic_load(&ctrl[0], __ATOMIC_RELAXED, __HIP_MEMORY_SCOPE_AGENT);
        } while (ch == 0);
        const int slice = (ch - 1 == xcd && r < NWORK) ? r : -1;
        s_slice = slice;

        // ---- canary handshake: verify the fast (local-L2) channel ----
        int mode = 0;
        if (slice >= 0) {
            ((volatile int*)ctrl)[16 + slice] = 0x5EED0000 | slice;  // fast store
            if (slice == 0) {
                mode = 1;
                for (int pass = 0; pass < (1 << 17); ++pass) {
                    bool all = true;
                    for (int rr = 0; rr < NWORK; ++rr)
                        if (((volatile int*)ctrl)[16 + rr] != (0x5EED0000 | rr)) { all = false; break; }
                    if (all) break;
                    if (pass == (1 << 17) - 1) mode = 2;   // fast channel dead
                }
                __hip_atomic_store(&ctrl[9], mode, __ATOMIC_RELAXED, __HIP_MEMORY_SCOPE_AGENT);
            } else {
                do {
                    mode = __hip_atomic_load(&ctrl[9], __ATOMIC_RELAXED, __HIP_MEMORY_SCOPE_AGENT);
                } while (mode == 0);      // rank0 always stores -> bounded
            }
        }
        s_mode = mode;
    }
    __syncthreads();
    const int b = s_slice;
    if (b < 0) return;
    const bool fast = (s_mode == 1);

    const int w = tid >> 6;             // wave 0..7
    const int l = tid & 63;             // lane

    __shared__ float hl[2][H_DIM];      // double-buffered swizzled h

    // ---- W fragment: rows wr0..wr0+3, k in [16l, 16l+16) ----
    const int wr0 = b * 32 + w * 4;
    v2f wreg[4][8];
#pragma unroll
    for (int j = 0; j < 4; ++j)
#pragma unroll
        for (int q = 0; q < 8; ++q)
            wreg[j][q] = *(const v2f*)(W + (size_t)(wr0 + j) * H_DIM + 16 * l + 2 * q);
    const float4 bh4 = *(const float4*)(bh + wr0);

    // ---- V fragment: rows vr0, vr0+1, same k-chunk ----
    const int vr0 = b * 16 + w * 2;
    v2f vreg[2][8];
#pragma unroll
    for (int m = 0; m < 2; ++m)
#pragma unroll
        for (int q = 0; q < 8; ++q)
            vreg[m][q] = *(const v2f*)(V + (size_t)(vr0 + m) * H_DIM + 16 * l + 2 * q);
    const float2 by2 = *(const float2*)(by + vr0);

    // ---- LDS addresses (dwords), quad-XOR swizzle ----
    int rdw[4];
#pragma unroll
    for (int q = 0; q < 4; ++q)
        rdw[q] = 16 * l + 4 * (q ^ ((l >> 1) & 3));
    const int c   = tid >> 3;
    const int qw  = (tid >> 1) & 3;
    const int wdw = 16 * c + 4 * (qw ^ ((c >> 1) & 3)) + 2 * (tid & 1);

    const bool pub = (l == 63);

    for (int t = 0; t < T_STEPS; ++t) {
        const int sb = (~t) & 1;
        float* hb = hl[sb];

        // lane63's U gathers (consumed after reduce; ~800 cy of slack)
        const int xt = xs[t];
        float u0 = 0.f, u1 = 0.f, u2 = 0.f, u3 = 0.f;
        if (pub) {
            u0 = U[(size_t)(wr0 + 0) * D_DIM + xt];
            u1 = U[(size_t)(wr0 + 1) * D_DIM + xt];
            u2 = U[(size_t)(wr0 + 2) * D_DIM + xt];
            u3 = U[(size_t)(wr0 + 3) * D_DIM + xt];
        }

        // ---- acquire h^{(t)}: poll own 2 tagged words ----
        float2 hpair;
        if (t == 0) {
            hpair = *(const float2*)(h0 + 2 * tid);
        } else {
            const size_t off = (size_t)((t - 1) & 1) * H_DIM + 2 * tid;
            const unsigned want = (unsigned)(t - 1);
            unsigned long long a, bq;
            if (fast) {
                const volatile unsigned long long* fp = htag + off;
                do { a = fp[0]; bq = fp[1]; }
                while ((unsigned)(a >> 32) != want || (unsigned)(bq >> 32) != want);
            } else {
                const unsigned long long* sp = htag + off;
                do {
                    a  = __hip_atomic_load(sp + 0, __ATOMIC_RELAXED, __HIP_MEMORY_SCOPE_AGENT);
                    bq = __hip_atomic_load(sp + 1, __ATOMIC_RELAXED, __HIP_MEMORY_SCOPE_AGENT);
                } while ((unsigned)(a >> 32) != want || (unsigned)(bq >> 32) != want);
            }
            hpair = make_float2(__uint_as_float((unsigned)a), __uint_as_float((unsigned)bq));
        }
        *(float2*)&hb[wdw] = hpair;
        __syncthreads();

        // ---- critical path: 16 h floats, pk-FMA matvec, DPP reduce ----
        float4 h4[4];
#pragma unroll
        for (int q = 0; q < 4; ++q) h4[q] = *(const float4*)&hb[rdw[q]];
        v2f h2[8];
#pragma unroll
        for (int q = 0; q < 4; ++q) {
            h2[2 * q]     = v2f{h4[q].x, h4[q].y};
            h2[2 * q + 1] = v2f{h4[q].z, h4[q].w};
        }

        float s0, s1, s2, s3;
        {
            v2f a[4];
#pragma unroll
            for (int j = 0; j < 4; ++j) {
                v2f e = v2f{0.f, 0.f}, o = v2f{0.f, 0.f};
#pragma unroll
                for (int q = 0; q < 4; ++q) {
                    e = __builtin_elementwise_fma(wreg[j][2 * q],     h2[2 * q],     e);
                    o = __builtin_elementwise_fma(wreg[j][2 * q + 1], h2[2 * q + 1], o);
                }
                a[j] = e + o;
            }
            s0 = a[0].x + a[0].y; s1 = a[1].x + a[1].y;
            s2 = a[2].x + a[2].y; s3 = a[3].x + a[3].y;
        }
        s0 = wave_sum_dpp(s0);
        s1 = wave_sum_dpp(s1);
        s2 = wave_sum_dpp(s2);
        s3 = wave_sum_dpp(s3);

        if (pub) {
            const unsigned long long hi = (unsigned long long)(unsigned)t << 32;
            unsigned long long p0 = hi | __float_as_uint(fast_tanh(s0 + bh4.x + u0));
            unsigned long long p1 = hi | __float_as_uint(fast_tanh(s1 + bh4.y + u1));
            unsigned long long p2 = hi | __float_as_uint(fast_tanh(s2 + bh4.z + u2));
            unsigned long long p3 = hi | __float_as_uint(fast_tanh(s3 + bh4.w + u3));
            unsigned long long* dst = htag + (size_t)(t & 1) * H_DIM + wr0;
            if (fast) {
                volatile unsigned long long* fd = dst;
                fd[0] = p0; fd[1] = p1; fd[2] = p2; fd[3] = p3;
            } else {
                __hip_atomic_store(dst + 0, p0, __ATOMIC_RELAXED, __HIP_MEMORY_SCOPE_AGENT);
                __hip_atomic_store(dst + 1, p1, __ATOMIC_RELAXED, __HIP_MEMORY_SCOPE_AGENT);
                __hip_atomic_store(dst + 2, p2, __ATOMIC_RELAXED, __HIP_MEMORY_SCOPE_AGENT);
                __hip_atomic_store(dst + 3, p3, __ATOMIC_RELAXED, __HIP_MEMORY_SCOPE_AGENT);
            }
        }

        // ---- hidden window: logits[t-1] from h2 registers ----
        if (t > 0) {
            float sv0, sv1;
            {
                v2f e0 = v2f{0.f, 0.f}, e1 = v2f{0.f, 0.f};
#pragma unroll
                for (int q = 0; q < 8; ++q) {
                    e0 = __builtin_elementwise_fma(vreg[0][q], h2[q], e0);
                    e1 = __builtin_elementwise_fma(vreg[1][q], h2[q], e1);
                }
                sv0 = e0.x + e0.y; sv1 = e1.x + e1.y;
            }
            sv0 = wave_sum_dpp(sv0);
            sv1 = wave_sum_dpp(sv1);
            if (pub)
                *(float2*)&out[(size_t)(t - 1) * O_DIM + vr0] =
                    make_float2(sv0 + by2.x, sv1 + by2.y);
        }
    }

    // ---- epilogue: h_T (tag T-1, parity 1) -> out tail + logits[T-1] ----
    {
        const size_t off = (size_t)((T_STEPS - 1) & 1) * H_DIM + 2 * tid;
        const unsigned want = (unsigned)(T_STEPS - 1);
        unsigned long long a, bq;
        if (fast) {
            const volatile unsigned long long* fp = htag + off;
            do { a = fp[0]; bq = fp[1]; }
            while ((unsigned)(a >> 32) != want || (unsigned)(bq >> 32) != want);
        } else {
            const unsigned long long* sp = htag + off;
            do {
                a  = __hip_atomic_load(sp + 0, __ATOMIC_RELAXED, __HIP_MEMORY_SCOPE_AGENT);
                bq = __hip_atomic_load(sp + 1, __ATOMIC_RELAXED, __HIP_MEMORY_SCOPE_AGENT);
            } while ((unsigned)(a >> 32) != want || (unsigned)(bq >> 32) != want);
        }
        float2 hpair = make_float2(__uint_as_float((unsigned)a),
                                   __uint_as_float((unsigned)bq));
        if (b == 0)
            *(float2*)&out[(size_t)T_STEPS * O_DIM + 2 * tid] = hpair;

        float* hb = hl[1];
        *(float2*)&hb[wdw] = hpair;
        __syncthreads();
        float4 h4[4];
#pragma unroll
        for (int q = 0; q < 4; ++q) h4[q] = *(const float4*)&hb[rdw[q]];
        v2f h2[8];
#pragma unroll
        for (int q = 0; q < 4; ++q) {
            h2[2 * q]     = v2f{h4[q].x, h4[q].y};
            h2[2 * q + 1] = v2f{h4[q].z, h4[q].w};
        }
        v2f e0 = v2f{0.f, 0.f}, e1 = v2f{0.f, 0.f};
#pragma unroll
        for (int q = 0; q < 8; ++q) {
            e0 = __builtin_elementwise_fma(vreg[0][q], h2[q], e0);
            e1 = __builtin_elementwise_fma(vreg[1][q], h2[q], e1);
        }
        float sv0 = wave_sum_dpp(e0.x + e0.y);
        float sv1 = wave_sum_dpp(e1.x + e1.y);
        if (pub)
            *(float2*)&out[(size_t)(T_STEPS - 1) * O_DIM + vr0] =
                make_float2(sv0 + by2.x, sv1 + by2.y);
    }
}

extern "C" void kernel_launch(void* const* d_in, const int* in_sizes, int n_in,
                              void* d_out, int out_size, void* d_ws, size_t ws_size,
                              hipStream_t stream) {
    const int*   xs = (const int*)d_in[0];
    const float* h0 = (const float*)d_in[1];
    const float* U  = (const float*)d_in[2];
    const float* W  = (const float*)d_in[3];
    const float* V  = (const float*)d_in[4];
    const float* bh = (const float*)d_in[5];
    const float* by = (const float*)d_in[6];
    float* out = (float*)d_out;

    // ws: [ctrl 256 B: chosen@0, cnt[8]@1..8, mode@9, canaries@16..47]
    //     [htag 2*1024 u64]
    int* ctrl = (int*)d_ws;
    unsigned long long* htag = (unsigned long long*)((char*)d_ws + 256);

    hipMemsetAsync(d_ws, 0, 256, stream);
    hipMemsetAsync((char*)d_ws + 256, 0xAA,
                   2 * H_DIM * sizeof(unsigned long long), stream);

    rnn_fused<<<NGRID, NTHR, 0, stream>>>(xs, h0, U, W, V, bh, by, out, ctrl, htag);
}